// Round 12
// baseline (55.133 us; speedup 1.0000x reference)
//
#include <hip/hip_runtime.h>
#include <math.h>

#define NP 16384
#define NG 2048
#define NC 17

#define TSH 3            // tile = 8x8 voxels in (x,y)
#define NTX 25
#define NTY 25
#define NTILE (NTX * NTY)   // 625
#define SEGC 32          // per-wave candidate cap (4 ranges of 512 prims)
#define CCAP (4 * SEGC)  // 128
#define SEGP 64          // per-wave point cap (4 ranges of 4096 points, mean ~6.5)
#define ROWF 40

#define GRIDSZ 0.4f
#define PCMINX -40.0f
#define PCMINY -40.0f
#define PCMINZ -1.0f
#define SCALE_MULTC 3.0f

// Dispatch 1: coalesced point->tile id (u16). Makes point discovery in the
// fused kernel a contiguous 2B/lane stream (128B per wave-iter).
__global__ __launch_bounds__(256)
void tile_of_kernel(const float* __restrict__ pts, unsigned short* __restrict__ tileOf) {
    int p = blockIdx.x * 256 + threadIdx.x;
    float x = pts[p * 3 + 0], y = pts[p * 3 + 1];
    int ix = (int)floorf((x - PCMINX) / GRIDSZ);
    int iy = (int)floorf((y - PCMINY) / GRIDSZ);
    tileOf[p] = (unsigned short)((iy >> TSH) * NTX + (ix >> TSH));
}

// Dispatch 2: one block (256 thr = 4 waves) per tile. All deterministic
// (ballot-compaction everywhere, fixed orders, no atomics).
// Row float4 layout: f0={mur0,mur1,mur2,r0} f1={r1..r4} f2={r5..r8}
// f3={1/sx,1/sy,1/sz,opa} f4={1/u,1/v,v/u,rad(int)} f5..f8=sem[0..15]
// f9={sem16, vx(int), vy(int), vz(int)}
__global__ __launch_bounds__(256, 4)
void fused_kernel(const float* __restrict__ pts,
                  const float* __restrict__ means3D,
                  const float* __restrict__ opas,
                  const float* __restrict__ uu,
                  const float* __restrict__ vv,
                  const float* __restrict__ semantics,
                  const float* __restrict__ scales,
                  const float* __restrict__ rot3D,
                  const unsigned short* __restrict__ tileOf,
                  float* __restrict__ out) {
    __shared__ __align__(16) float rowsF[CCAP * ROWF];   // 20480 B
    __shared__ float part[3][64][21];                    // 16128 B
    __shared__ unsigned short candSeg[4][SEGC];
    __shared__ unsigned short ptSeg[4][SEGP];
    __shared__ unsigned short ptLin[4 * SEGP];
    __shared__ int wcC[4], wcP[4];

    const int tid = threadIdx.x;
    const int lane = tid & 63;
    const int w = tid >> 6;
    const int b = blockIdx.x;
    const int tx = b % NTX, ty = b / NTX;

    // ---- Phase A: prim->tile ballot bin (wave w scans prims [w*512, +512)) ----
    unsigned cl = 0;
#pragma unroll 2
    for (int it = 0; it < 8; ++it) {
        int g = w * 512 + it * 64 + lane;
        float mx = means3D[g * 3 + 0], my = means3D[g * 3 + 1];
        float sx = scales[g * 3 + 0], sy = scales[g * 3 + 1], sz = scales[g * 3 + 2];
        int vx = (int)floorf((mx - PCMINX) / GRIDSZ);
        int vy = (int)floorf((my - PCMINY) / GRIDSZ);
        float smax = fmaxf(sx, fmaxf(sy, sz));
        int rad = (int)ceilf(smax * SCALE_MULTC / GRIDSZ);
        if (rad < 1) rad = 1;
        bool ov = (((vx - rad) >> TSH) <= tx) & (((vx + rad) >> TSH) >= tx) &
                  (((vy - rad) >> TSH) <= ty) & (((vy + rad) >> TSH) >= ty);
        unsigned long long bal = __ballot(ov);
        if (ov) {
            int pos = (int)cl + (int)__popcll(bal & ((1ull << lane) - 1ull));
            if (pos < SEGC) candSeg[w][pos] = (unsigned short)g;
        }
        cl += (unsigned)__popcll(bal);
    }
    if (lane == 0) wcC[w] = min((int)cl, SEGC);
    __syncthreads();

    const int c0 = wcC[0], c1 = wcC[1], c2 = wcC[2], c3 = wcC[3];
    const int o1 = c0, o2 = o1 + c1, o3 = o2 + c2;
    const int totalCand = o3 + c3;

    // ---- Phase A2: stage candidate rows (thread i -> candidate i) ----
    if (tid < totalCand) {
        int s, idx;
        if (tid < o1)      { s = 0; idx = tid; }
        else if (tid < o2) { s = 1; idx = tid - o1; }
        else if (tid < o3) { s = 2; idx = tid - o2; }
        else               { s = 3; idx = tid - o3; }
        int g = (int)candSeg[s][idx];
        float mx = means3D[g * 3 + 0], my = means3D[g * 3 + 1], mz = means3D[g * 3 + 2];
        float sx = scales[g * 3 + 0], sy = scales[g * 3 + 1], sz = scales[g * 3 + 2];
        float r[9];
#pragma unroll
        for (int i = 0; i < 9; ++i) r[i] = rot3D[g * 9 + i];
        float sem[NC];
#pragma unroll
        for (int c = 0; c < NC; ++c) sem[c] = semantics[(size_t)g * NC + c];
        float ug = uu[g], vg = vv[g], op = opas[g];
        int vx = (int)floorf((mx - PCMINX) / GRIDSZ);
        int vy = (int)floorf((my - PCMINY) / GRIDSZ);
        int vz = (int)floorf((mz - PCMINZ) / GRIDSZ);
        float smax = fmaxf(sx, fmaxf(sy, sz));
        int rad = (int)ceilf(smax * SCALE_MULTC / GRIDSZ);
        if (rad < 1) rad = 1;

        float4* Rv = (float4*)(rowsF + tid * ROWF);
        Rv[0] = make_float4(mx * r[0] + my * r[3] + mz * r[6],
                            mx * r[1] + my * r[4] + mz * r[7],
                            mx * r[2] + my * r[5] + mz * r[8], r[0]);
        Rv[1] = make_float4(r[1], r[2], r[3], r[4]);
        Rv[2] = make_float4(r[5], r[6], r[7], r[8]);
        Rv[3] = make_float4(1.0f / sx, 1.0f / sy, 1.0f / sz, op);
        Rv[4] = make_float4(1.0f / ug, 1.0f / vg, vg / ug, __int_as_float(rad));
        Rv[5] = make_float4(sem[0], sem[1], sem[2], sem[3]);
        Rv[6] = make_float4(sem[4], sem[5], sem[6], sem[7]);
        Rv[7] = make_float4(sem[8], sem[9], sem[10], sem[11]);
        Rv[8] = make_float4(sem[12], sem[13], sem[14], sem[15]);
        Rv[9] = make_float4(sem[16], __int_as_float(vx), __int_as_float(vy),
                            __int_as_float(vz));
    }

    // ---- Phase B: point ballot-compact (wave w scans tileOf[w*4096, +4096)) ----
    unsigned pl = 0;
#pragma unroll 4
    for (int it = 0; it < 64; ++it) {
        int p = w * 4096 + it * 64 + lane;
        bool ov = (tileOf[p] == (unsigned short)b);
        unsigned long long bal = __ballot(ov);
        if (ov) {
            int pos = (int)pl + (int)__popcll(bal & ((1ull << lane) - 1ull));
            if (pos < SEGP) ptSeg[w][pos] = (unsigned short)p;
        }
        pl += (unsigned)__popcll(bal);
    }
    if (lane == 0) wcP[w] = min((int)pl, SEGP);
    __syncthreads();

    const int p0c = wcP[0], p1c = wcP[1], p2c = wcP[2], p3c = wcP[3];
    const int q1 = p0c, q2 = q1 + p1c, q3 = q2 + p2c;
    const int totalPts = q3 + p3c;
    if (totalPts == 0) return;   // uniform across block

    {
        int off = (w == 0) ? 0 : (w == 1) ? q1 : (w == 2) ? q2 : q3;
        int myc = (w == 0) ? p0c : (w == 1) ? p1c : (w == 2) ? p2c : p3c;
        if (lane < myc) ptLin[off + lane] = ptSeg[w][lane];
    }
    __syncthreads();

    // ---- Phase C: eval. Wave w owns candidate range [kb, ke). ----
    const int kb = (w == 0) ? 0 : (w == 1) ? o1 : (w == 2) ? o2 : o3;
    const int ke = kb + ((w == 0) ? c0 : (w == 1) ? c1 : (w == 2) ? c2 : c3);

    const int nr = (totalPts + 63) >> 6;
    for (int r = 0; r < nr; ++r) {
        int j = r * 64 + lane;
        bool act = j < totalPts;
        int p = act ? (int)ptLin[j] : 0;
        float px = pts[p * 3 + 0], py = pts[p * 3 + 1], pz = pts[p * 3 + 2];
        int ix = (int)floorf((px - PCMINX) / GRIDSZ);
        int iy = (int)floorf((py - PCMINY) / GRIDSZ);
        int iz = (int)floorf((pz - PCMINZ) / GRIDSZ);

        float density = 0.0f, logbin = 0.0f;
        float acc[NC];
#pragma unroll
        for (int c = 0; c < NC; ++c) acc[c] = 0.0f;

        for (int k = kb; k < ke; ++k) {
            const float4* Rv = (const float4*)(rowsF + k * ROWF);
            float4 f0 = Rv[0], f1 = Rv[1], f2 = Rv[2], f3 = Rv[3], f4 = Rv[4];
            float4 f5 = Rv[5], f6 = Rv[6], f7 = Rv[7], f8 = Rv[8], f9 = Rv[9];
            int cheb = max(max(abs(ix - __float_as_int(f9.y)),
                               abs(iy - __float_as_int(f9.z))),
                           abs(iz - __float_as_int(f9.w)));
            float l0 = px * f0.w + py * f1.z + pz * f2.y - f0.x;
            float l1 = px * f1.x + py * f1.w + pz * f2.z - f0.y;
            float l2 = px * f1.y + py * f2.x + pz * f2.w - f0.z;
            float t0 = l0 * f3.x, t1 = l1 * f3.y, t2 = l2 * f3.z;
            float s0 = t0 * t0 + 1e-8f;
            float s1 = t1 * t1 + 1e-8f;
            float s2 = t2 * t2 + 1e-8f;
            float f = __powf(__powf(s0, f4.y) + __powf(s1, f4.y), f4.z) +
                      __powf(s2, f4.x);
            float a = f3.w * __expf(-0.5f * f);
            a = (cheb <= __float_as_int(f4.w)) ? a : 0.0f;
            density += a;
            acc[0]  = fmaf(a, f5.x, acc[0]);  acc[1]  = fmaf(a, f5.y, acc[1]);
            acc[2]  = fmaf(a, f5.z, acc[2]);  acc[3]  = fmaf(a, f5.w, acc[3]);
            acc[4]  = fmaf(a, f6.x, acc[4]);  acc[5]  = fmaf(a, f6.y, acc[5]);
            acc[6]  = fmaf(a, f6.z, acc[6]);  acc[7]  = fmaf(a, f6.w, acc[7]);
            acc[8]  = fmaf(a, f7.x, acc[8]);  acc[9]  = fmaf(a, f7.y, acc[9]);
            acc[10] = fmaf(a, f7.z, acc[10]); acc[11] = fmaf(a, f7.w, acc[11]);
            acc[12] = fmaf(a, f8.x, acc[12]); acc[13] = fmaf(a, f8.y, acc[13]);
            acc[14] = fmaf(a, f8.z, acc[14]); acc[15] = fmaf(a, f8.w, acc[15]);
            acc[16] = fmaf(a, f9.x, acc[16]);
            logbin += __logf(1.0f - fminf(a, 1.0f - 1e-4f));
        }

        if (w > 0) {
            float* pp = part[w - 1][lane];
#pragma unroll
            for (int c = 0; c < NC; ++c) pp[c] = acc[c];
            pp[17] = density;
            pp[18] = logbin;
        }
        __syncthreads();
        if (w == 0 && act) {
#pragma unroll
            for (int s = 0; s < 3; ++s) {
                const float* pp = part[s][lane];
#pragma unroll
                for (int c = 0; c < NC; ++c) acc[c] += pp[c];
                density += pp[17];
                logbin += pp[18];
            }
            float inv = 1.0f / (density + 1e-9f);
#pragma unroll
            for (int c = 0; c < NC; ++c) out[(size_t)p * NC + c] = acc[c] * inv;
            out[(size_t)NP * NC + p] = 1.0f - expf(logbin);
            out[(size_t)NP * NC + NP + p] = density;
        }
        __syncthreads();
    }
}

// ---- fallback (ws too small): monolithic kernel ----
__global__ __launch_bounds__(64)
void agg_kernel_fb(const float* __restrict__ pts,
                   const float* __restrict__ means3D,
                   const float* __restrict__ opas,
                   const float* __restrict__ uu,
                   const float* __restrict__ vv,
                   const float* __restrict__ semantics,
                   const float* __restrict__ scales,
                   const float* __restrict__ rot3D,
                   float* __restrict__ out) {
    int p = blockIdx.x * 64 + threadIdx.x;
    if (p >= NP) return;
    float px = pts[p * 3 + 0], py = pts[p * 3 + 1], pz = pts[p * 3 + 2];
    int pix = (int)floorf((px - PCMINX) / GRIDSZ);
    int piy = (int)floorf((py - PCMINY) / GRIDSZ);
    int piz = (int)floorf((pz - PCMINZ) / GRIDSZ);
    float density = 0.0f, logbin = 0.0f;
    float acc[NC];
#pragma unroll
    for (int c = 0; c < NC; ++c) acc[c] = 0.0f;
    for (int g = 0; g < NG; ++g) {
        float mx = means3D[g * 3 + 0], my = means3D[g * 3 + 1], mz = means3D[g * 3 + 2];
        float sx = scales[g * 3 + 0], sy = scales[g * 3 + 1], sz = scales[g * 3 + 2];
        int vx = (int)floorf((mx - PCMINX) / GRIDSZ);
        int vy = (int)floorf((my - PCMINY) / GRIDSZ);
        int vz = (int)floorf((mz - PCMINZ) / GRIDSZ);
        float smax = fmaxf(sx, fmaxf(sy, sz));
        int rad = (int)ceilf(smax * SCALE_MULTC / GRIDSZ);
        rad = rad < 1 ? 1 : rad;
        int cheb = max(abs(pix - vx), max(abs(piy - vy), abs(piz - vz)));
        if (cheb <= rad) {
            const float* r = rot3D + (size_t)g * 9;
            float dx = px - mx, dy = py - my, dz = pz - mz;
            float l0 = dx * r[0] + dy * r[3] + dz * r[6];
            float l1 = dx * r[1] + dy * r[4] + dz * r[7];
            float l2 = dx * r[2] + dy * r[5] + dz * r[8];
            float t0 = l0 / sx, t1 = l1 / sy, t2 = l2 / sz;
            float s0 = t0 * t0 + 1e-8f, s1 = t1 * t1 + 1e-8f, s2 = t2 * t2 + 1e-8f;
            float ie1 = 1.0f / uu[g], ie2 = 1.0f / vv[g], e21 = vv[g] * ie1;
            float f = __powf(__powf(s0, ie2) + __powf(s1, ie2), e21) + __powf(s2, ie1);
            float a = opas[g] * __expf(-0.5f * f);
            density += a;
            const float* sg = semantics + (size_t)g * NC;
#pragma unroll
            for (int c = 0; c < NC; ++c) acc[c] = fmaf(a, sg[c], acc[c]);
            logbin += __logf(1.0f - fminf(a, 1.0f - 1e-4f));
        }
    }
    float inv = 1.0f / (density + 1e-9f);
#pragma unroll
    for (int c = 0; c < NC; ++c) out[(size_t)p * NC + c] = acc[c] * inv;
    out[(size_t)NP * NC + p] = 1.0f - expf(logbin);
    out[(size_t)NP * NC + NP + p] = density;
}

extern "C" void kernel_launch(void* const* d_in, const int* in_sizes, int n_in,
                              void* d_out, int out_size, void* d_ws, size_t ws_size,
                              hipStream_t stream) {
    const float* pts       = (const float*)d_in[0];
    const float* means3D   = (const float*)d_in[1];
    const float* opas      = (const float*)d_in[2];
    const float* uu        = (const float*)d_in[3];
    const float* vv        = (const float*)d_in[4];
    const float* semantics = (const float*)d_in[5];
    const float* scales    = (const float*)d_in[6];
    const float* rot3D     = (const float*)d_in[7];
    float* out = (float*)d_out;

    size_t tileOfBytes = (size_t)NP * sizeof(unsigned short);   // 32 KB

    if (ws_size >= tileOfBytes) {
        unsigned short* tileOf = (unsigned short*)d_ws;
        tile_of_kernel<<<NP / 256, 256, 0, stream>>>(pts, tileOf);
        fused_kernel<<<NTILE, 256, 0, stream>>>(pts, means3D, opas, uu, vv, semantics,
                                                scales, rot3D, tileOf, out);
    } else {
        agg_kernel_fb<<<NP / 64, 64, 0, stream>>>(pts, means3D, opas, uu, vv, semantics,
                                                  scales, rot3D, out);
    }
}

// Round 13
// 39.088 us; speedup vs baseline: 1.4105x; 1.4105x over previous
//
#include <hip/hip_runtime.h>
#include <math.h>

#define NP 16384
#define NG 2048
#define NC 17

#define TSH 3            // tile = 8x8 voxels in (x,y)
#define NTX 25
#define NTY 25
#define NTILE (NTX * NTY)   // 625
#define SEGC 32          // per-wave candidate cap in bin (4 ranges of 512 prims)
#define CCAP 128         // per-tile candidate cap (mean ~16)
#define ROWF 40          // floats per candidate row

#define GRIDSZ 0.4f
#define PCMINX -40.0f
#define PCMINY -40.0f
#define PCMINZ -1.0f
#define SCALE_MULTC 3.0f

// Row layout (40 floats, 10 float4s):
// f0={mur0,mur1,mur2,r0} f1={r1,r2,r3,r4} f2={r5,r6,r7,r8}
// f3={1/sx,1/sy,1/sz,opa} f4={1/u,1/v,v/u,sem16} f5..f8=sem[0..15]
// f9={vx,vy,vz,rad} (ints bitcast)

// Dispatch 1: one block per tile. Ballot-compact overlapping prims (ascending
// g, deterministic, no atomics, no memset), then thread i builds candidate
// row i directly into the ws row table.
__global__ __launch_bounds__(256)
void bin_kernel(const float* __restrict__ means3D, const float* __restrict__ opas,
                const float* __restrict__ uu, const float* __restrict__ vv,
                const float* __restrict__ semantics, const float* __restrict__ scales,
                const float* __restrict__ rot3D,
                unsigned int* __restrict__ candCnt, float* __restrict__ rowTbl) {
    __shared__ unsigned short candSeg[4][SEGC];
    __shared__ int wc[4];
    const int tid = threadIdx.x;
    const int lane = tid & 63;
    const int w = tid >> 6;
    const int b = blockIdx.x;
    const int tx = b % NTX, ty = b / NTX;

    unsigned cl = 0;
#pragma unroll
    for (int it = 0; it < 8; ++it) {
        int g = w * 512 + it * 64 + lane;
        float mx = means3D[g * 3 + 0], my = means3D[g * 3 + 1];
        float sx = scales[g * 3 + 0], sy = scales[g * 3 + 1], sz = scales[g * 3 + 2];
        int vx = (int)floorf((mx - PCMINX) / GRIDSZ);
        int vy = (int)floorf((my - PCMINY) / GRIDSZ);
        float smax = fmaxf(sx, fmaxf(sy, sz));
        int rad = (int)ceilf(smax * SCALE_MULTC / GRIDSZ);
        if (rad < 1) rad = 1;
        // arithmetic >> floors negatives
        bool ov = (((vx - rad) >> TSH) <= tx) & (((vx + rad) >> TSH) >= tx) &
                  (((vy - rad) >> TSH) <= ty) & (((vy + rad) >> TSH) >= ty);
        unsigned long long bal = __ballot(ov);
        if (ov) {
            int pos = (int)cl + (int)__popcll(bal & ((1ull << lane) - 1ull));
            if (pos < SEGC) candSeg[w][pos] = (unsigned short)g;
        }
        cl += (unsigned)__popcll(bal);
    }
    if (lane == 0) wc[w] = min((int)cl, SEGC);
    __syncthreads();

    const int c0 = wc[0], c1 = wc[1], c2 = wc[2], c3 = wc[3];
    const int o1 = c0, o2 = o1 + c1, o3 = o2 + c2;
    const int total = o3 + c3;   // <= 128

    if (tid < total) {
        int s, idx;
        if (tid < o1)      { s = 0; idx = tid; }
        else if (tid < o2) { s = 1; idx = tid - o1; }
        else if (tid < o3) { s = 2; idx = tid - o2; }
        else               { s = 3; idx = tid - o3; }
        int g = (int)candSeg[s][idx];
        float mx = means3D[g * 3 + 0], my = means3D[g * 3 + 1], mz = means3D[g * 3 + 2];
        float sx = scales[g * 3 + 0], sy = scales[g * 3 + 1], sz = scales[g * 3 + 2];
        float r[9];
#pragma unroll
        for (int i = 0; i < 9; ++i) r[i] = rot3D[g * 9 + i];
        float sem[NC];
#pragma unroll
        for (int c = 0; c < NC; ++c) sem[c] = semantics[(size_t)g * NC + c];
        float ug = uu[g], vg = vv[g], op = opas[g];
        int vx = (int)floorf((mx - PCMINX) / GRIDSZ);
        int vy = (int)floorf((my - PCMINY) / GRIDSZ);
        int vz = (int)floorf((mz - PCMINZ) / GRIDSZ);
        float smax = fmaxf(sx, fmaxf(sy, sz));
        int rad = (int)ceilf(smax * SCALE_MULTC / GRIDSZ);
        if (rad < 1) rad = 1;

        float4* Rv = (float4*)(rowTbl + ((size_t)b * CCAP + tid) * ROWF);
        Rv[0] = make_float4(mx * r[0] + my * r[3] + mz * r[6],
                            mx * r[1] + my * r[4] + mz * r[7],
                            mx * r[2] + my * r[5] + mz * r[8], r[0]);
        Rv[1] = make_float4(r[1], r[2], r[3], r[4]);
        Rv[2] = make_float4(r[5], r[6], r[7], r[8]);
        Rv[3] = make_float4(1.0f / sx, 1.0f / sy, 1.0f / sz, op);
        Rv[4] = make_float4(1.0f / ug, 1.0f / vg, vg / ug, sem[16]);
        Rv[5] = make_float4(sem[0], sem[1], sem[2], sem[3]);
        Rv[6] = make_float4(sem[4], sem[5], sem[6], sem[7]);
        Rv[7] = make_float4(sem[8], sem[9], sem[10], sem[11]);
        Rv[8] = make_float4(sem[12], sem[13], sem[14], sem[15]);
        Rv[9] = make_float4(__int_as_float(vx), __int_as_float(vy),
                            __int_as_float(vz), __int_as_float(rad));
    }
    if (tid == 0) candCnt[b] = (unsigned)total;
}

__device__ __forceinline__ float eval_row(const float* __restrict__ R,
                                          float px, float py, float pz,
                                          int ix, int iy, int iz) {
    const float4* Rv = (const float4*)R;
    float4 f0 = Rv[0], f1 = Rv[1], f2 = Rv[2], f3 = Rv[3], f4 = Rv[4], f9 = Rv[9];
    int cheb = max(max(abs(ix - __float_as_int(f9.x)),
                       abs(iy - __float_as_int(f9.y))),
                   abs(iz - __float_as_int(f9.z)));
    float l0 = px * f0.w + py * f1.z + pz * f2.y - f0.x;
    float l1 = px * f1.x + py * f1.w + pz * f2.z - f0.y;
    float l2 = px * f1.y + py * f2.x + pz * f2.w - f0.z;
    float t0 = l0 * f3.x, t1 = l1 * f3.y, t2 = l2 * f3.z;
    float s0 = t0 * t0 + 1e-8f;
    float s1 = t1 * t1 + 1e-8f;
    float s2 = t2 * t2 + 1e-8f;
    float f = __powf(__powf(s0, f4.y) + __powf(s1, f4.y), f4.z) + __powf(s2, f4.x);
    float a = f3.w * __expf(-0.5f * f);
    return (cheb <= __float_as_int(f9.w)) ? a : 0.0f;
}

// Dispatch 2: ONE WAVE PER POINT (16384 waves). Lane k evaluates candidate k
// of the point's tile (predicated; whole candidate set in one parallel step).
// Butterfly shfl reduce for density/logbin; semantics matvec with lane=channel
// and __shfl-broadcast a_k + coalesced row reads. Fully deterministic.
__global__ __launch_bounds__(256)
void point_kernel(const float* __restrict__ pts,
                  const unsigned int* __restrict__ candCnt,
                  const float* __restrict__ rowTbl,
                  float* __restrict__ out) {
    const int lane = threadIdx.x & 63;
    const int w = threadIdx.x >> 6;
    const int p = blockIdx.x * 4 + w;

    float px = pts[p * 3 + 0], py = pts[p * 3 + 1], pz = pts[p * 3 + 2];
    int ix = (int)floorf((px - PCMINX) / GRIDSZ);
    int iy = (int)floorf((py - PCMINY) / GRIDSZ);
    int iz = (int)floorf((pz - PCMINZ) / GRIDSZ);
    int t = (iy >> TSH) * NTX + (ix >> TSH);
    int n = (int)candCnt[t];
    const float* base = rowTbl + (size_t)t * CCAP * ROWF;

    float a0 = 0.0f, a1 = 0.0f;
    if (lane < n)      a0 = eval_row(base + (size_t)lane * ROWF, px, py, pz, ix, iy, iz);
    if (lane + 64 < n) a1 = eval_row(base + (size_t)(lane + 64) * ROWF, px, py, pz, ix, iy, iz);

    float asum = a0 + a1;
    float lb = __logf(1.0f - fminf(a0, 1.0f - 1e-4f)) +
               __logf(1.0f - fminf(a1, 1.0f - 1e-4f));
#pragma unroll
    for (int o = 1; o < 64; o <<= 1) {
        asum += __shfl_xor(asum, o);
        lb += __shfl_xor(lb, o);
    }

    // semantics matvec: lane c accumulates channel c
    float acc = 0.0f;
    const int cofs = (lane == 16) ? 19 : (20 + lane);   // sem16 lives at R[19]
    int nk0 = min(n, 64);
    for (int k = 0; k < nk0; ++k) {
        float ak = __shfl(a0, k);
        if (lane < NC) acc = fmaf(ak, base[(size_t)k * ROWF + cofs], acc);
    }
    for (int k = 64; k < n; ++k) {
        float ak = __shfl(a1, k - 64);
        if (lane < NC) acc = fmaf(ak, base[(size_t)k * ROWF + cofs], acc);
    }

    if (lane < NC) out[(size_t)p * NC + lane] = acc / (asum + 1e-9f);
    if (lane == 0) {
        out[(size_t)NP * NC + p] = 1.0f - expf(lb);
        out[(size_t)NP * NC + NP + p] = asum;
    }
}

// ---- fallback (ws too small): monolithic kernel ----
__global__ __launch_bounds__(64)
void agg_kernel_fb(const float* __restrict__ pts,
                   const float* __restrict__ means3D,
                   const float* __restrict__ opas,
                   const float* __restrict__ uu,
                   const float* __restrict__ vv,
                   const float* __restrict__ semantics,
                   const float* __restrict__ scales,
                   const float* __restrict__ rot3D,
                   float* __restrict__ out) {
    int p = blockIdx.x * 64 + threadIdx.x;
    if (p >= NP) return;
    float px = pts[p * 3 + 0], py = pts[p * 3 + 1], pz = pts[p * 3 + 2];
    int pix = (int)floorf((px - PCMINX) / GRIDSZ);
    int piy = (int)floorf((py - PCMINY) / GRIDSZ);
    int piz = (int)floorf((pz - PCMINZ) / GRIDSZ);
    float density = 0.0f, logbin = 0.0f;
    float acc[NC];
#pragma unroll
    for (int c = 0; c < NC; ++c) acc[c] = 0.0f;
    for (int g = 0; g < NG; ++g) {
        float mx = means3D[g * 3 + 0], my = means3D[g * 3 + 1], mz = means3D[g * 3 + 2];
        float sx = scales[g * 3 + 0], sy = scales[g * 3 + 1], sz = scales[g * 3 + 2];
        int vx = (int)floorf((mx - PCMINX) / GRIDSZ);
        int vy = (int)floorf((my - PCMINY) / GRIDSZ);
        int vz = (int)floorf((mz - PCMINZ) / GRIDSZ);
        float smax = fmaxf(sx, fmaxf(sy, sz));
        int rad = (int)ceilf(smax * SCALE_MULTC / GRIDSZ);
        rad = rad < 1 ? 1 : rad;
        int cheb = max(abs(pix - vx), max(abs(piy - vy), abs(piz - vz)));
        if (cheb <= rad) {
            const float* r = rot3D + (size_t)g * 9;
            float dx = px - mx, dy = py - my, dz = pz - mz;
            float l0 = dx * r[0] + dy * r[3] + dz * r[6];
            float l1 = dx * r[1] + dy * r[4] + dz * r[7];
            float l2 = dx * r[2] + dy * r[5] + dz * r[8];
            float t0 = l0 / sx, t1 = l1 / sy, t2 = l2 / sz;
            float s0 = t0 * t0 + 1e-8f, s1 = t1 * t1 + 1e-8f, s2 = t2 * t2 + 1e-8f;
            float ie1 = 1.0f / uu[g], ie2 = 1.0f / vv[g], e21 = vv[g] * ie1;
            float f = __powf(__powf(s0, ie2) + __powf(s1, ie2), e21) + __powf(s2, ie1);
            float a = opas[g] * __expf(-0.5f * f);
            density += a;
            const float* sg = semantics + (size_t)g * NC;
#pragma unroll
            for (int c = 0; c < NC; ++c) acc[c] = fmaf(a, sg[c], acc[c]);
            logbin += __logf(1.0f - fminf(a, 1.0f - 1e-4f));
        }
    }
    float inv = 1.0f / (density + 1e-9f);
#pragma unroll
    for (int c = 0; c < NC; ++c) out[(size_t)p * NC + c] = acc[c] * inv;
    out[(size_t)NP * NC + p] = 1.0f - expf(logbin);
    out[(size_t)NP * NC + NP + p] = density;
}

extern "C" void kernel_launch(void* const* d_in, const int* in_sizes, int n_in,
                              void* d_out, int out_size, void* d_ws, size_t ws_size,
                              hipStream_t stream) {
    const float* pts       = (const float*)d_in[0];
    const float* means3D   = (const float*)d_in[1];
    const float* opas      = (const float*)d_in[2];
    const float* uu        = (const float*)d_in[3];
    const float* vv        = (const float*)d_in[4];
    const float* semantics = (const float*)d_in[5];
    const float* scales    = (const float*)d_in[6];
    const float* rot3D     = (const float*)d_in[7];
    float* out = (float*)d_out;

    size_t cntBytes = ((size_t)NTILE * sizeof(unsigned int) + 255) & ~(size_t)255; // 2.6 KB
    size_t rowBytes = (size_t)NTILE * CCAP * ROWF * sizeof(float);                 // 12.8 MB
    size_t need = cntBytes + rowBytes;

    if (ws_size >= need) {
        unsigned int* candCnt = (unsigned int*)d_ws;
        float* rowTbl = (float*)((char*)d_ws + cntBytes);
        bin_kernel<<<NTILE, 256, 0, stream>>>(means3D, opas, uu, vv, semantics,
                                              scales, rot3D, candCnt, rowTbl);
        point_kernel<<<NP / 4, 256, 0, stream>>>(pts, candCnt, rowTbl, out);
    } else {
        agg_kernel_fb<<<NP / 64, 64, 0, stream>>>(pts, means3D, opas, uu, vv, semantics,
                                                  scales, rot3D, out);
    }
}